// Round 6
// baseline (368.821 us; speedup 1.0000x reference)
//
#include <hip/hip_runtime.h>
#include <math.h>

// Problem constants (match reference)
constexpr int EN = 200000;   // edges == nodes
constexpr int D  = 128;      // embedding dim
constexpr int R  = 4;        // relation types
constexpr float NEG = 0.01f;

static inline int ceil_div(int a, int b) { return (a + b - 1) / b; }

typedef __attribute__((ext_vector_type(8)))  __bf16 bf16x8;
typedef __attribute__((ext_vector_type(16))) float  f32x16;

// ---------- bf16 helpers (RNE) ----------
__device__ __forceinline__ unsigned short f2bf(float f) {
    union { float f; unsigned u; } v; v.f = f;
    unsigned u = v.u + 0x7fffu + ((v.u >> 16) & 1u);
    return (unsigned short)(u >> 16);
}
__device__ __forceinline__ unsigned pack2bf(float a, float b) {
    return (unsigned)f2bf(a) | ((unsigned)f2bf(b) << 16);
}
__device__ __forceinline__ float bflo(unsigned m) { return __uint_as_float(m << 16); }
__device__ __forceinline__ float bfhi(unsigned m) { return __uint_as_float(m & 0xffff0000u); }

// ---------- histogram: col degree (int) + relation counts ----------
__global__ void k_cnt(const int* __restrict__ col, const int* __restrict__ etype,
                      int* __restrict__ cnt, int* __restrict__ rcnt, int n) {
    __shared__ int lr[R];
    int t = threadIdx.x;
    if (t < R) lr[t] = 0;
    __syncthreads();
    int e = blockIdx.x * 256 + t;
    if (e < n) {
        atomicAdd(&cnt[col[e]], 1);
        atomicAdd(&lr[etype[e]], 1);
    }
    __syncthreads();
    if (t < R) atomicAdd(&rcnt[t], lr[t]);
}

// ---------- W pre-swizzle to 32x32x16 MFMA A-frag bf16 ----------
// slab (r,step,mt): 64 lanes x 8 shorts; value = W[k = step*16 + (l>>5)*8 + j][n = mt*32 + (l&31)]
__device__ __forceinline__ void wswz_one(const float* __restrict__ w,
                                         unsigned short* __restrict__ wsw, int t) {
    int lane = t & 63, mt = (t >> 6) & 3, step = (t >> 8) & 7, r = t >> 11;
    int h = lane >> 5, n = mt * 32 + (lane & 31);
    union { unsigned short us[8]; uint4 u4; } o;
    #pragma unroll
    for (int j = 0; j < 8; ++j) {
        int k = step * 16 + h * 8 + j;
        o.us[j] = f2bf(w[((size_t)r * D + k) * D + n]);
    }
    *(uint4*)(wsw + (size_t)t * 8) = o.u4;
}

// ---------- scan stage 1 (+ fused weight prep in extra blocks) ----------
__global__ void k_scan1(const int* __restrict__ cnt, int* __restrict__ part, int n, int nScan,
                        const float* __restrict__ w1, const float* __restrict__ w2,
                        const float* __restrict__ w3,
                        unsigned short* __restrict__ w2b, unsigned short* __restrict__ w3b,
                        float* __restrict__ s1) {
    if (blockIdx.x >= nScan) {
        int t = (blockIdx.x - nScan) * 256 + threadIdx.x;
        if (t < 8192) {
            wswz_one(w2, w2b, t);
        } else if (t < 16384) {
            wswz_one(w3, w3b, t - 8192);
        } else if (t < 16896) {
            int t2 = t - 16384;           // 0..511: colsum(W1)
            int r = t2 >> 7, j = t2 & (D - 1);
            float s = 0.f;
            for (int k = 0; k < D; ++k) s += w1[((r << 7) + k) * D + j];
            s1[t2] = s;
        }
        return;
    }
    __shared__ int sm[256];
    int t = threadIdx.x;
    int base = blockIdx.x * 1024 + t * 4;
    int s = 0;
    #pragma unroll
    for (int i = 0; i < 4; ++i) { int idx = base + i; if (idx < n) s += cnt[idx]; }
    sm[t] = s; __syncthreads();
    for (int off = 128; off > 0; off >>= 1) {
        if (t < off) sm[t] += sm[t + off];
        __syncthreads();
    }
    if (t == 0) part[blockIdx.x] = sm[0];
}

// ---------- scan stage 2 (+ relation bases + bkpk pad zero) ----------
__global__ void k_scan2(int* __restrict__ part, int nb,
                        const int* __restrict__ rcnt, int* __restrict__ rbase,
                        int* __restrict__ cursor, int* __restrict__ col_start,
                        uint4* __restrict__ bkpk) {
    __shared__ int sm[256];
    int t = threadIdx.x;
    sm[t] = (t < nb) ? part[t] : 0;
    __syncthreads();
    for (int off = 1; off < 256; off <<= 1) {
        int u = 0;
        if (t >= off) u = sm[t - off];
        __syncthreads();
        sm[t] += u;
        __syncthreads();
    }
    int ex = (t > 0) ? sm[t - 1] : 0;
    if (t < nb) part[t] = ex;
    if (t == 0) {
        int s = 0;
        for (int r = 0; r < R; ++r) { rbase[r] = s; cursor[r] = s; s += rcnt[r]; }
        rbase[R] = s;
        col_start[EN] = EN;
    }
    if (t >= 64 && t < 128)
        bkpk[EN + t - 64] = (uint4){0u, 0u, 0u, 0u};   // pad: safe gather, coef 0
}

// ---------- scan stage 3: col_start (+ ccur zeroing) ----------
__global__ void k_scan3(const int* __restrict__ cnt, const int* __restrict__ part,
                        int* __restrict__ col_start, int* __restrict__ ccur, int n) {
    __shared__ int sm[256];
    int t = threadIdx.x;
    int base = blockIdx.x * 1024 + t * 4;
    int v[4]; int s = 0;
    #pragma unroll
    for (int i = 0; i < 4; ++i) { int idx = base + i; v[i] = (idx < n) ? cnt[idx] : 0; s += v[i]; }
    sm[t] = s; __syncthreads();
    for (int off = 1; off < 256; off <<= 1) {
        int u = 0;
        if (t >= off) u = sm[t - off];
        __syncthreads();
        sm[t] += u;
        __syncthreads();
    }
    int ex = ((t > 0) ? sm[t - 1] : 0) + part[blockIdx.x];
    #pragma unroll
    for (int i = 0; i < 4; ++i) {
        int idx = base + i;
        if (idx < n) { col_start[idx] = ex; ex += v[i]; ccur[idx] = 0; }
    }
}

// ---------- bucket by relation + col-sorted placement + coef (packed) ----------
// bkpk[pos] = {src_row, dst(sorted pos), coef_bits, 0}  (relation-bucket order)
// spk[sp]   = {coef_bits, type}                         (col-sorted order)
__global__ void k_bucket(const int* __restrict__ row, const int* __restrict__ col,
                         const int* __restrict__ etype, const float* __restrict__ attr,
                         const int* __restrict__ cnt, const int* __restrict__ col_start,
                         int* __restrict__ cursor, int* __restrict__ ccur,
                         uint4* __restrict__ bkpk, uint2* __restrict__ spk, int n) {
    __shared__ int lcnt[R];
    __shared__ int lbase[R];
    int t = threadIdx.x;
    if (t < R) lcnt[t] = 0;
    __syncthreads();
    int e = blockIdx.x * 256 + t;
    int r = 0, rank = 0, c = 0, rw = 0;
    float cf = 0.f;
    if (e < n) {
        r = etype[e];
        rank = atomicAdd(&lcnt[r], 1);
        c = col[e]; rw = row[e];
        int dr = cnt[rw], dc = cnt[c];
        float a = (dr > 0) ? rsqrtf((float)dr) : 0.f;
        float b = (dc > 0) ? rsqrtf((float)dc) : 0.f;
        cf = attr[e] * a * b;
    }
    __syncthreads();
    if (t < R) lbase[t] = atomicAdd(&cursor[t], lcnt[t]);
    __syncthreads();
    if (e < n) {
        int pos = lbase[r] + rank;                       // relation-bucket position
        int sp = col_start[c] + atomicAdd(&ccur[c], 1);  // col-sorted position
        bkpk[pos] = (uint4){(unsigned)rw, (unsigned)sp, __float_as_uint(cf), 0u};
        spk[sp] = (uint2){__float_as_uint(cf), (unsigned)r};
    }
}

// ---------- layer 1 gather: xb = bf16(z1) ----------
__global__ void k_phase1(const float* __restrict__ s1, const float* __restrict__ b1,
                         const int* __restrict__ col_start,
                         const uint2* __restrict__ spk,
                         unsigned* __restrict__ xb32) {
    __shared__ float ls1[R * D];
    __shared__ float lb[D];
    int t = threadIdx.x;
    ls1[t] = s1[t];
    ls1[t + 256] = s1[t + 256];
    if (t < D) lb[t] = b1[t];
    __syncthreads();
    int lane = t & 63;
    int c = blockIdx.x * 4 + (t >> 6);
    if (c >= EN) return;
    int st = col_start[c], en = col_start[c + 1];
    float a0 = 0.f, a1 = 0.f;
    for (int p = st; p < en; ++p) {
        uint2 s = spk[p];
        float cf = __uint_as_float(s.x);
        int tp = (int)s.y;
        a0 += cf * ls1[tp * D + lane * 2];
        a1 += cf * ls1[tp * D + lane * 2 + 1];
    }
    a0 += lb[lane * 2]; a1 += lb[lane * 2 + 1];
    a0 = (a0 > 0.f) ? a0 : NEG * a0;
    a1 = (a1 > 0.f) ? a1 : NEG * a1;
    xb32[(size_t)c * 64 + lane] = pack2bf(a0, a1);
}

// ---------- MFMA GEMM (32x32x16): one wave per 32-edge tile ----------
// D^T = W^T (A-operand, pre-swizzled) x x^T (B-operand, row gather).
// Lane l: edge = tile*32 + (l&31); k-half h = l>>5.
// C/D: col = l&31 (edge), row(n in mt tile) = (reg&3) + 8*(reg>>2) + 4*h.
// Epilogue: per-wave LDS transpose -> 256 B coalesced row stores.
__global__ __launch_bounds__(256)
void k_gemm(const unsigned short* __restrict__ xb, const unsigned short* __restrict__ wsw,
            const uint4* __restrict__ bkpk, const int* __restrict__ rbase,
            unsigned short* __restrict__ msgb) {
    const int r = blockIdx.y;
    const int base = rbase[r];
    const int cnt = rbase[r + 1] - base;
    const int t = threadIdx.x;
    const int tile = blockIdx.x * 4 + (t >> 6);
    __shared__ unsigned short xpose[4][32 * 136];   // 34816 B; wave-private regions
    if (tile * 32 >= cnt) return;           // wave-uniform early exit
    const int l = t & 63, h = l >> 5, e = l & 31;
    const int eidx = tile * 32 + e;
    const bool valid = eidx < cnt;
    const int p = base + eidx;              // < EN + 64 (bkpk padded)
    uint4 meta = bkpk[p];
    const int srow = (int)meta.x;
    const int dp = (int)meta.y;
    const float cf = __uint_as_float(meta.z);

    // B-frags: x[edge][k]; 8 independent 16 B loads per lane (lane halves split k)
    const unsigned short* xrow = xb + (size_t)srow * D;
    bf16x8 xf[8];
    #pragma unroll
    for (int st = 0; st < 8; ++st)
        xf[st] = *(const bf16x8*)(xrow + st * 16 + h * 8);

    // A-frags: swizzled W, L1/L2-resident
    const unsigned short* wr = wsw + (size_t)r * 16384 + (size_t)l * 8;

    f32x16 acc[4];
    #pragma unroll
    for (int mt = 0; mt < 4; ++mt)
        #pragma unroll
        for (int i = 0; i < 16; ++i) acc[mt][i] = 0.f;

    #pragma unroll
    for (int st = 0; st < 8; ++st) {
        #pragma unroll
        for (int mt = 0; mt < 4; ++mt) {
            bf16x8 wf = *(const bf16x8*)(wr + (size_t)(st * 4 + mt) * 512);
            acc[mt] = __builtin_amdgcn_mfma_f32_32x32x16_bf16(wf, xf[st], acc[mt], 0, 0, 0);
        }
    }

    // epilogue: scale, pack, transpose through wave-private LDS, coalesced store
    unsigned short* lbuf = xpose[t >> 6];
    const float c = valid ? cf : 0.f;
    #pragma unroll
    for (int mt = 0; mt < 4; ++mt) {
        #pragma unroll
        for (int rg = 0; rg < 4; ++rg) {
            uint2 u;
            u.x = pack2bf(acc[mt][rg * 4 + 0] * c, acc[mt][rg * 4 + 1] * c);
            u.y = pack2bf(acc[mt][rg * 4 + 2] * c, acc[mt][rg * 4 + 3] * c);
            int nb = mt * 32 + rg * 8 + h * 4;
            *(uint2*)&lbuf[e * 136 + nb] = u;
        }
    }
    const int dpv = valid ? dp : EN;        // invalid edges -> dump row
    #pragma unroll
    for (int ro = 0; ro < 8; ++ro) {
        int el = ro * 4 + (l >> 4);
        uint4 v = *(const uint4*)&lbuf[el * 136 + (l & 15) * 8];
        int rdp = __shfl(dpv, el);
        *(uint4*)(msgb + (size_t)rdp * D + (l & 15) * 8) = v;
    }
}

// ---------- sequential gather + bias + leaky + combine (layers 2,3) ----------
// mode 2: z1 = xb; xb = z2 (bf16); zsum = z1+z2 (bf16)
// mode 3: dout = (1 + zsum + z3) * 0.25 (fp32)
__global__ void k_phaseB(const unsigned* __restrict__ msgb32, const float* __restrict__ bias,
                         const int* __restrict__ col_start,
                         unsigned* __restrict__ xb32, unsigned* __restrict__ zs32,
                         float* __restrict__ dout, int mode) {
    __shared__ float lb[D];
    int t = threadIdx.x;
    if (t < D) lb[t] = bias[t];
    __syncthreads();
    int lane = t & 63;
    int c = blockIdx.x * 4 + (t >> 6);
    if (c >= EN) return;
    int st = col_start[c], en = col_start[c + 1];
    float a0 = 0.f, a1 = 0.f;
    for (int p = st; p < en; ++p) {
        unsigned m = msgb32[(size_t)p * 64 + lane];
        a0 += bflo(m); a1 += bfhi(m);
    }
    a0 += lb[lane * 2]; a1 += lb[lane * 2 + 1];
    a0 = (a0 > 0.f) ? a0 : NEG * a0;
    a1 = (a1 > 0.f) ? a1 : NEG * a1;
    size_t ix = (size_t)c * 64 + lane;
    if (mode == 2) {
        unsigned z1 = xb32[ix];
        xb32[ix] = pack2bf(a0, a1);
        zs32[ix] = pack2bf(bflo(z1) + a0, bfhi(z1) + a1);
    } else {
        unsigned zs = zs32[ix];
        float2 o;
        o.x = (1.f + bflo(zs) + a0) * 0.25f;
        o.y = (1.f + bfhi(zs) + a1) * 0.25f;
        ((float2*)(dout + (size_t)c * D))[lane] = o;
    }
}

extern "C" void kernel_launch(void* const* d_in, const int* in_sizes, int n_in,
                              void* d_out, int out_size, void* d_ws, size_t ws_size,
                              hipStream_t stream) {
    const int*   eidx = (const int*)d_in[0];     // [2, E]
    const int*   row  = eidx;
    const int*   col  = eidx + EN;
    const int*   etyp = (const int*)d_in[1];
    const float* attr = (const float*)d_in[2];
    const float* w1   = (const float*)d_in[3];
    const float* b1   = (const float*)d_in[4];
    const float* w2   = (const float*)d_in[5];
    const float* b2   = (const float*)d_in[6];
    const float* w3   = (const float*)d_in[7];
    const float* b3   = (const float*)d_in[8];
    float* dout = (float*)d_out;

    // workspace layout (~163 MB of the ~409.6 MB ws)
    char* wsb = (char*)d_ws;
    size_t off = 0;
    unsigned short* msgb = (unsigned short*)(wsb + off); off += (size_t)(EN + 1) * D * 2 + 512;
    unsigned short* xb   = (unsigned short*)(wsb + off); off += (size_t)EN * D * 2;
    unsigned short* zsb  = (unsigned short*)(wsb + off); off += (size_t)EN * D * 2;
    int*   col_start = (int*)(wsb + off); off += 800032;
    int*   cnt       = (int*)(wsb + off); off += (size_t)EN * 4;
    int*   rcnt      = (int*)(wsb + off); off += 16;      // contiguous after cnt!
    uint4* bkpk      = (uint4*)(wsb + off); off += (size_t)(EN + 64) * 16;
    uint2* spk       = (uint2*)(wsb + off); off += (size_t)EN * 8;
    unsigned short* w2b = (unsigned short*)(wsb + off); off += 131072;
    unsigned short* w3b = (unsigned short*)(wsb + off); off += 131072;
    int*   part      = (int*)(wsb + off); off += 1024;
    int*   rbase     = (int*)(wsb + off); off += 32;
    int*   cursor    = (int*)(wsb + off); off += 16;
    float* s1        = (float*)(wsb + off); off += (size_t)R * D * 4;
    int*   ccur      = (int*)msgb;   // aliased: msgb not live until GEMM layer 2

    const int nE = EN;
    const int nBlkE = ceil_div(nE, 256);       // 782
    const int nScan = ceil_div(nE, 1024);      // 196
    dim3 blk(256);

    // histogram (one memset covers cnt + rcnt, contiguous)
    hipMemsetAsync(cnt, 0, (size_t)(nE + 4) * 4, stream);
    k_cnt<<<nBlkE, blk, 0, stream>>>(col, etyp, cnt, rcnt, nE);

    // scan cnt -> col_start (scan1 also swizzles W2/W3 + colsum(W1);
    // scan2 also does relation bases + bkpk pad; scan3 zeroes ccur)
    k_scan1<<<nScan + 66, blk, 0, stream>>>(cnt, part, nE, nScan,
                                            w1, w2, w3, w2b, w3b, s1);
    k_scan2<<<1, blk, 0, stream>>>(part, nScan, rcnt, rbase, cursor, col_start, bkpk);
    k_scan3<<<nScan, blk, 0, stream>>>(cnt, part, col_start, ccur, nE);

    // bucket + col-sort placement (+ coef), packed outputs
    k_bucket<<<nBlkE, blk, 0, stream>>>(row, col, etyp, attr, cnt, col_start,
                                        cursor, ccur, bkpk, spk, nE);

    // layer 1 (x = ones)
    k_phase1<<<ceil_div(nE, 4), blk, 0, stream>>>(s1, b1, col_start, spk, (unsigned*)xb);

    // layers 2,3
    dim3 gg(ceil_div(ceil_div(nE, 32), 4), R);
    k_gemm<<<gg, blk, 0, stream>>>(xb, w2b, bkpk, rbase, msgb);
    k_phaseB<<<ceil_div(nE, 4), blk, 0, stream>>>((const unsigned*)msgb, b2, col_start,
                                                  (unsigned*)xb, (unsigned*)zsb, dout, 2);
    k_gemm<<<gg, blk, 0, stream>>>(xb, w3b, bkpk, rbase, msgb);
    k_phaseB<<<ceil_div(nE, 4), blk, 0, stream>>>((const unsigned*)msgb, b3, col_start,
                                                  (unsigned*)xb, (unsigned*)zsb, dout, 3);
}